// Round 6
// baseline (730.832 us; speedup 1.0000x reference)
//
#include <hip/hip_runtime.h>
#include <hip/hip_bf16.h>
#include <math.h>

// Problem constants
#define QN 300
#define BN 2
#define SN 4096
#define DN 256
#define HN 8
#define HD 32
#define BH 16
#define DFF 2048

typedef __attribute__((ext_vector_type(8))) short s16x8;
typedef __attribute__((ext_vector_type(4))) float f32x4;

// ---------------- helpers ----------------
__device__ inline float wred_sum(float v) {
#pragma unroll
    for (int m = 32; m > 0; m >>= 1) v += __shfl_xor(v, m);
    return v;
}
__device__ inline ushort f2b(float x) {
    union { __hip_bfloat16 h; ushort u; } c;
    c.h = __float2bfloat16(x);
    return c.u;
}
__device__ inline float b2f(ushort u) {
    union { unsigned int i; float f; } c;
    c.i = ((unsigned int)u) << 16;
    return c.f;
}

// ---------------- add + layernorm ----------------
__global__ __launch_bounds__(256) void addln_kernel(
    const float* __restrict__ a, const float* __restrict__ b,
    const float* __restrict__ g, const float* __restrict__ be,
    float* __restrict__ out_ln, float* __restrict__ out_sum)
{
    int row = blockIdx.x;
    int t = threadIdx.x;
    float v = a[row * DN + t] + b[row * DN + t];
    if (out_sum) out_sum[row * DN + t] = v;
    float s = wred_sum(v);
    float s2 = wred_sum(v * v);
    __shared__ float ws1[4], ws2[4];
    int wave = t >> 6, lane = t & 63;
    if (lane == 0) { ws1[wave] = s; ws2[wave] = s2; }
    __syncthreads();
    float S1 = ws1[0] + ws1[1] + ws1[2] + ws1[3];
    float S2 = ws2[0] + ws2[1] + ws2[2] + ws2[3];
    float mean = S1 * (1.0f / DN);
    float var = S2 * (1.0f / DN) - mean * mean;
    float inv = rsqrtf(var + 1e-5f);
    out_ln[row * DN + t] = (v - mean) * inv * g[t] + be[t];
}

// ---------------- fp32 -> bf16 conversions ----------------
__global__ void f2bf_kernel(const float* __restrict__ in, ushort* __restrict__ out, int n4)
{
    int i = blockIdx.x * blockDim.x + threadIdx.x;
    int stride = gridDim.x * blockDim.x;
    for (; i < n4; i += stride) {
        float4 x = ((const float4*)in)[i];
        ushort4 o;
        o.x = f2b(x.x); o.y = f2b(x.y); o.z = f2b(x.z); o.w = f2b(x.w);
        ((ushort4*)out)[i] = o;
    }
}
__global__ void addvec_bf16_kernel(const float* __restrict__ a, const float* __restrict__ b,
                                   ushort* __restrict__ out, int n4)
{
    int i = blockIdx.x * blockDim.x + threadIdx.x;
    int stride = gridDim.x * blockDim.x;
    for (; i < n4; i += stride) {
        float4 x = ((const float4*)a)[i];
        float4 y = ((const float4*)b)[i];
        ushort4 o;
        o.x = f2b(x.x + y.x); o.y = f2b(x.y + y.y);
        o.z = f2b(x.z + y.z); o.w = f2b(x.w + y.w);
        ((ushort4*)out)[i] = o;
    }
}

// ---------------- xq = x1+query_pos ; xo = x1+masked(query_pos) ----------------
__global__ __launch_bounds__(256) void build_xq_xo(
    const float* __restrict__ x1, const float* __restrict__ qp,
    const int* __restrict__ ro1, const int* __restrict__ ro2,
    float* __restrict__ xq, float* __restrict__ xo)
{
    int row = blockIdx.x, t = threadIdx.x;
    int q = row >> 1, b = row & 1;
    const int* ro = b ? ro2 : ro1;
    bool msk = (ro[q * 4 + 0] == 0) || (ro[q * 4 + 1] == 0) ||
               (ro[q * 4 + 2] == 0) || (ro[q * 4 + 3] == 0);
    float xv = x1[row * DN + t], qv = qp[row * DN + t];
    xq[row * DN + t] = xv + qv;
    xo[row * DN + t] = xv + (msk ? 0.0f : qv);
}

// ---------------- fp32 small GEMM 32x32 ----------------
// MODE 0: plain fp32; 1: relu fp32; 2: fp32 head layout [bh][seqLen][32] (*scale);
// MODE 4: bf16 head layout [bh][seqLen][32] (*scale)
template <int MODE>
__global__ __launch_bounds__(256) void gemm_small(
    const float* __restrict__ A, const float* __restrict__ W,
    const float* __restrict__ bias, float* __restrict__ C,
    int M, int N, int K, int seqLen, float scale)
{
    __shared__ float As[16][36];
    __shared__ float Bs[16][36];
    int bm = blockIdx.x * 32;
    int bn = blockIdx.y * 32;
    int t = threadIdx.x;
    int sr = (t & 127) >> 2;
    int sc = (t & 3) << 2;
    bool isB = t >= 128;
    int tm = (t >> 4) << 1;
    int tn = (t & 15) << 1;
    float acc[2][2] = {};
    int srcRow = (isB ? bn : bm) + sr;
    int lim = isB ? N : M;
    const float* src = isB ? W : A;
    for (int k0 = 0; k0 < K; k0 += 16) {
        float4 v = make_float4(0, 0, 0, 0);
        if (srcRow < lim) v = *(const float4*)&src[(size_t)srcRow * K + k0 + sc];
        __syncthreads();
        float (*Ts)[36] = isB ? Bs : As;
        Ts[sc + 0][sr] = v.x; Ts[sc + 1][sr] = v.y; Ts[sc + 2][sr] = v.z; Ts[sc + 3][sr] = v.w;
        __syncthreads();
#pragma unroll
        for (int kk = 0; kk < 16; kk++) {
            float2 a = *(const float2*)&As[kk][tm];
            float2 b = *(const float2*)&Bs[kk][tn];
            acc[0][0] = fmaf(a.x, b.x, acc[0][0]); acc[0][1] = fmaf(a.x, b.y, acc[0][1]);
            acc[1][0] = fmaf(a.y, b.x, acc[1][0]); acc[1][1] = fmaf(a.y, b.y, acc[1][1]);
        }
    }
#pragma unroll
    for (int i = 0; i < 2; i++) {
        int m = bm + tm + i;
        if (m >= M) continue;
#pragma unroll
        for (int j = 0; j < 2; j++) {
            int n = bn + tn + j;
            float v = acc[i][j] + bias[n];
            if (MODE == 1) v = fmaxf(v, 0.0f);
            if (MODE == 2) {
                v *= scale;
                int b = m & 1, seq = m >> 1, h = n >> 5, hd = n & 31;
                C[((size_t)(b * 8 + h) * seqLen + seq) * 32 + hd] = v;
            } else if (MODE == 4) {
                v *= scale;
                int b = m & 1, seq = m >> 1, h = n >> 5, hd = n & 31;
                ushort* Cb = (ushort*)C;
                Cb[((size_t)(b * 8 + h) * seqLen + seq) * 32 + hd] = f2b(v);
            } else {
                C[(size_t)m * N + n] = v;
            }
        }
    }
}

// ---------------- bf16 MFMA GEMM for K/V projections (verified r5) ----------------
__global__ __launch_bounds__(256) void gemm_bf16_mfma(
    const ushort* __restrict__ A, const ushort* __restrict__ W,
    const float* __restrict__ bias, ushort* __restrict__ C, int seqLen)
{
    __shared__ ushort As[64][40];
    __shared__ ushort Ws[64][40];
    int bm = blockIdx.x * 64;
    int bn = blockIdx.y * 64;
    int t = threadIdx.x;
    int w = t >> 6, lane = t & 63;
    int lr = lane & 15, lg = lane >> 4;
    int sr = t >> 2, sg = t & 3;

    f32x4 acc[4];
#pragma unroll
    for (int f = 0; f < 4; f++) acc[f] = (f32x4)0.0f;

    for (int k0 = 0; k0 < 256; k0 += 32) {
        int4 av = *(const int4*)&A[((size_t)(bm + sr)) * 256 + k0 + sg * 8];
        int4 wv = *(const int4*)&W[((size_t)(bn + sr)) * 256 + k0 + sg * 8];
        __syncthreads();
        *(int4*)&As[sr][sg * 8] = av;
        *(int4*)&Ws[sr][sg * 8] = wv;
        __syncthreads();
        s16x8 af = *(const s16x8*)&As[w * 16 + lr][lg * 8];
#pragma unroll
        for (int f = 0; f < 4; f++) {
            s16x8 bf = *(const s16x8*)&Ws[f * 16 + lr][lg * 8];
            acc[f] = __builtin_amdgcn_mfma_f32_16x16x32_bf16(af, bf, acc[f], 0, 0, 0);
        }
    }
#pragma unroll
    for (int f = 0; f < 4; f++) {
#pragma unroll
        for (int j = 0; j < 4; j++) {
            int m = bm + w * 16 + lg * 4 + j;
            int n = bn + f * 16 + lr;
            float v = acc[f][j] + bias[n];
            int b = m & 1, seq = m >> 1, h = n >> 5, hd = n & 31;
            C[(((size_t)(b * 8 + h) * seqLen) + seq) * 32 + hd] = f2b(v);
        }
    }
}

// ---------------- small heads ----------------
__global__ __launch_bounds__(64) void small_heads(
    const float* __restrict__ ln4, const float* __restrict__ h2,
    const float* __restrict__ p2W, const float* __restrict__ p2b,
    const float* __restrict__ p3W, const float* __restrict__ p3b,
    const float* __restrict__ p1W2, const float* __restrict__ p1b2,
    const float* __restrict__ h_w,
    float* __restrict__ ref_inter_out, float* __restrict__ ref_out,
    float* __restrict__ point, float* __restrict__ scale2)
{
    int row = blockIdx.x;       // q*2+b
    int lane = threadIdx.x;     // 64
    __shared__ float rA[DN], rH[DN];
    __shared__ float po[16], sc[16], ri[2];
#pragma unroll
    for (int i = 0; i < 4; i++) {
        rA[lane + i * 64] = ln4[row * DN + lane + i * 64];
        rH[lane + i * 64] = h2[row * DN + lane + i * 64];
    }
    __syncthreads();
    for (int j = 0; j < 16; j++) {
        float p = 0;
#pragma unroll
        for (int i = 0; i < 4; i++) { int d = lane + i * 64; p = fmaf(rA[d], p2W[j * DN + d], p); }
        p = wred_sum(p);
        if (lane == 0) po[j] = p + p2b[j];
    }
    for (int j = 0; j < 16; j++) {
        float p = 0;
#pragma unroll
        for (int i = 0; i < 4; i++) { int d = lane + i * 64; p = fmaf(rA[d], p3W[j * DN + d], p); }
        p = wred_sum(p);
        if (lane == 0) sc[j] = p + p3b[j];
    }
    for (int j = 0; j < 2; j++) {
        float p = 0;
#pragma unroll
        for (int i = 0; i < 4; i++) { int d = lane + i * 64; p = fmaf(rH[d], p1W2[j * DN + d], p); }
        p = wred_sum(p);
        if (lane == 0) ri[j] = p + p1b2[j];
    }
    __syncthreads();
    int q = row >> 1, b = row & 1;
    float sig0 = 1.0f / (1.0f + expf(-ri[0]));
    float sig1 = 1.0f / (1.0f + expf(-ri[1]));
    float rx = h_w[b * 2 + 0] * sig0 * (1.0f / 32.0f);
    float ry = h_w[b * 2 + 1] * sig1 * (1.0f / 32.0f);
    if (lane < 2) ref_inter_out[row * 2 + lane] = ri[lane];
    if (lane < 16) {
        float rc = (lane & 1) ? ry : rx;
        ref_out[row * 16 + lane] = rc;
        int pidx = (q * 16 + b * 8 + (lane >> 1)) * 2 + (lane & 1);
        point[pidx] = rc + po[lane];
        float s = sc[lane];
        scale2[pidx] = s * s;
    }
}

// ---------------- fp32 split flash attention (proven) ----------------
template <bool BIAS, bool BF16KV>
__global__ __launch_bounds__(256) void attn_split(
    const float* __restrict__ qp, const void* __restrict__ kp_, const void* __restrict__ vp_,
    const float* __restrict__ point, const float* __restrict__ scale2,
    const float* __restrict__ grid_xy,
    float* __restrict__ pacc, float* __restrict__ pm, float* __restrict__ pl,
    int S, int L, int tilesPerChunk, int ROWS)
{
    const int bh = blockIdx.y;
    const int q0 = blockIdx.x * 16;
    const int chunk = blockIdx.z;
    const int nT = (S + 63) >> 6;
    const int t_begin = chunk * tilesPerChunk;
    const int t_end = min(nT, t_begin + tilesPerChunk);

    __shared__ float Qs[16][36];
    __shared__ float Ks[64][36];
    __shared__ float Vt[32][68];
    __shared__ float Ps[16][68];
    __shared__ float sf_s[16];
    __shared__ float pt_s[16][2], sc_s[16][2];

    int t = threadIdx.x;
    int wave = t >> 6, lane = t & 63;

    {
        int qi = t >> 4, d = (t & 15) * 2;
        int gq = q0 + qi;
        float2 v = make_float2(0, 0);
        if (gq < L) v = *(const float2*)&qp[((size_t)bh * L + gq) * 32 + d];
        Qs[qi][d] = v.x; Qs[qi][d + 1] = v.y;
        if (BIAS && t < 32) {
            int qi2 = t >> 1, c = t & 1;
            int gq2 = q0 + qi2;
            pt_s[qi2][c] = (gq2 < L) ? point[(gq2 * 16 + bh) * 2 + c] : 0.0f;
            sc_s[qi2][c] = (gq2 < L) ? scale2[(gq2 * 16 + bh) * 2 + c] : 0.0f;
        }
    }
    float m_run[4], l_run[4];
#pragma unroll
    for (int r = 0; r < 4; r++) { m_run[r] = -INFINITY; l_run[r] = 0.0f; }
    int pq = t >> 4, pd = t & 15;
    float2 acc = make_float2(0.0f, 0.0f);
    __syncthreads();

    for (int tt = t_begin; tt < t_end; tt++) {
        int s0 = tt << 6;
        if (BF16KV) {
            const ushort* kp = (const ushort*)kp_;
            const ushort* vp = (const ushort*)vp_;
            int s = t >> 2, dg = (t & 3) * 8;
            int gs = s0 + s;
            int4 kv = make_int4(0, 0, 0, 0), vv = make_int4(0, 0, 0, 0);
            if (gs < S) {
                kv = *(const int4*)&kp[((size_t)bh * S + gs) * 32 + dg];
                vv = *(const int4*)&vp[((size_t)bh * S + gs) * 32 + dg];
            }
            union { int4 v; ushort u[8]; } ck, cv;
            ck.v = kv; cv.v = vv;
#pragma unroll
            for (int jj = 0; jj < 8; jj++) {
                Ks[s][dg + jj] = b2f(ck.u[jj]);
                Vt[dg + jj][s] = b2f(cv.u[jj]);
            }
        } else {
            const float* kp = (const float*)kp_;
            const float* vp = (const float*)vp_;
#pragma unroll
            for (int rep = 0; rep < 2; rep++) {
                int f = t + rep * 256;
                int s = f >> 3, dc = (f & 7) * 4;
                int gs = s0 + s;
                float4 kv = make_float4(0, 0, 0, 0), vv = make_float4(0, 0, 0, 0);
                if (gs < S) {
                    kv = *(const float4*)&kp[((size_t)bh * S + gs) * 32 + dc];
                    vv = *(const float4*)&vp[((size_t)bh * S + gs) * 32 + dc];
                }
                Ks[s][dc + 0] = kv.x; Ks[s][dc + 1] = kv.y; Ks[s][dc + 2] = kv.z; Ks[s][dc + 3] = kv.w;
                Vt[dc + 0][s] = vv.x; Vt[dc + 1][s] = vv.y; Vt[dc + 2][s] = vv.z; Vt[dc + 3][s] = vv.w;
            }
        }
        float gx = 0, gy = 0;
        if (BIAS) {
            int gs = s0 + lane;
            if (gs < S) { gx = grid_xy[gs * 2 + 0]; gy = grid_xy[gs * 2 + 1]; }
        }
        __syncthreads();

        float kreg[32];
#pragma unroll
        for (int d4 = 0; d4 < 8; d4++) {
            float4 kk = *(const float4*)&Ks[lane][d4 * 4];
            kreg[d4 * 4 + 0] = kk.x; kreg[d4 * 4 + 1] = kk.y;
            kreg[d4 * 4 + 2] = kk.z; kreg[d4 * 4 + 3] = kk.w;
        }
        bool svalid = (s0 + lane) < S;
#pragma unroll
        for (int r = 0; r < 4; r++) {
            int qi = wave * 4 + r;
            float sum = 0;
#pragma unroll
            for (int d4 = 0; d4 < 8; d4++) {
                float4 qv = *(const float4*)&Qs[qi][d4 * 4];
                sum = fmaf(qv.x, kreg[d4 * 4 + 0], sum);
                sum = fmaf(qv.y, kreg[d4 * 4 + 1], sum);
                sum = fmaf(qv.z, kreg[d4 * 4 + 2], sum);
                sum = fmaf(qv.w, kreg[d4 * 4 + 3], sum);
            }
            if (BIAS) {
                float dx = pt_s[qi][0] - gx, dy = pt_s[qi][1] - gy;
                sum -= (sc_s[qi][0] * dx * dx + sc_s[qi][1] * dy * dy) * 0.125f;
            }
            float l = svalid ? sum : -INFINITY;
            float tmax = l;
#pragma unroll
            for (int m = 32; m > 0; m >>= 1) tmax = fmaxf(tmax, __shfl_xor(tmax, m));
            float m_new = fmaxf(m_run[r], tmax);
            float p = __expf(l - m_new);
            float psum = wred_sum(p);
            float sfv = __expf(m_run[r] - m_new);
            l_run[r] = l_run[r] * sfv + psum;
            m_run[r] = m_new;
            Ps[qi][lane] = p;
            if (lane == 0) sf_s[qi] = sfv;
        }
        __syncthreads();

        {
            float sfv = sf_s[pq];
            float ax = acc.x * sfv, ay = acc.y * sfv;
            int d0 = pd * 2;
#pragma unroll
            for (int s4 = 0; s4 < 16; s4++) {
                float4 p4 = *(const float4*)&Ps[pq][s4 * 4];
                float4 va = *(const float4*)&Vt[d0][s4 * 4];
                float4 vb = *(const float4*)&Vt[d0 + 1][s4 * 4];
                ax = fmaf(p4.x, va.x, ax); ax = fmaf(p4.y, va.y, ax);
                ax = fmaf(p4.z, va.z, ax); ax = fmaf(p4.w, va.w, ax);
                ay = fmaf(p4.x, vb.x, ay); ay = fmaf(p4.y, vb.y, ay);
                ay = fmaf(p4.z, vb.z, ay); ay = fmaf(p4.w, vb.w, ay);
            }
            acc.x = ax; acc.y = ay;
        }
        __syncthreads();
    }

    if (lane == 0) {
#pragma unroll
        for (int r = 0; r < 4; r++) {
            int row = q0 + wave * 4 + r;
            size_t pidx = (size_t)(chunk * 16 + bh) * ROWS + row;
            pm[pidx] = m_run[r];
            pl[pidx] = l_run[r];
        }
    }
    {
        int row = q0 + pq;
        size_t pidx = (size_t)(chunk * 16 + bh) * ROWS + row;
        *(float2*)&pacc[pidx * 32 + pd * 2] = acc;
    }
}

// ---------------- HYBRID: MFMA QK^T + in-reg softmax + DIRECT bias + scalar fp32 PV ----
// Bisects attn_mfma: QK-half kept (bf16 Q, MFMA QK, in-reg softmax), PV-half replaced
// by the proven scalar path (P fp32 in LDS, V fp32 transposed). Direct bias form.
template <bool BIAS>
__global__ __launch_bounds__(256) void attn_qkmfma(
    const ushort* __restrict__ qp, const ushort* __restrict__ kp, const ushort* __restrict__ vp,
    const float* __restrict__ point, const float* __restrict__ scale2,
    const float* __restrict__ grid_xy,
    float* __restrict__ pacc, float* __restrict__ pm, float* __restrict__ pl,
    int S, int L, int tilesPerChunk, int ROWS)
{
    const int bh = blockIdx.y;
    const int q0 = blockIdx.x * 64;
    const int chunk = blockIdx.z;
    const int nT = (S + 63) >> 6;
    const int t_begin = chunk * tilesPerChunk;
    const int t_end = min(nT, t_begin + tilesPerChunk);

    __shared__ ushort Ks[64][40];   // K bf16 [s][d]
    __shared__ float Vt[32][68];    // V fp32 transposed [d][s]
    __shared__ float Ps[64][68];    // P fp32 [q_local][s]
    __shared__ float sf_s[64];
    __shared__ float gq2[64][2];    // gx, gy per s
    __shared__ float qc[64][4];     // px, py, sx, sy per local q

    int t = threadIdx.x;
    int w = t >> 6, lane = t & 63;
    int lr = lane & 15, lg = lane >> 4;
    int sr = t >> 2, sg = t & 3;

    // Q fragment (bf16, A-operand: lane row lr, k-octet lg)
    s16x8 qfrag;
    {
        int qrow = q0 + w * 16 + lr;
        if (qrow < L) qfrag = *(const s16x8*)&qp[((size_t)bh * L + qrow) * 32 + lg * 8];
        else qfrag = (s16x8)(short)0;
    }

    float px[4], py[4], sx[4], sy[4];
    if (BIAS) {
        if (t < 64) {
            int q = q0 + t;
            float a = 0, b = 0, c = 0, d = 0;
            if (q < L) {
                a = point[(q * 16 + bh) * 2 + 0];
                b = point[(q * 16 + bh) * 2 + 1];
                c = scale2[(q * 16 + bh) * 2 + 0];
                d = scale2[(q * 16 + bh) * 2 + 1];
            }
            qc[t][0] = a; qc[t][1] = b; qc[t][2] = c; qc[t][3] = d;
        }
        __syncthreads();
#pragma unroll
        for (int j = 0; j < 4; j++) {
            int ql = w * 16 + lg * 4 + j;
            px[j] = qc[ql][0]; py[j] = qc[ql][1];
            sx[j] = qc[ql][2]; sy[j] = qc[ql][3];
        }
    }

    float m_run[4], l_run[4];
#pragma unroll
    for (int j = 0; j < 4; j++) { m_run[j] = -INFINITY; l_run[j] = 0.0f; }

    // scalar PV ownership: 2 q rows x 4 d per thread
    int q2 = (t >> 3) * 2;          // 0,2,..,62
    int dq = (t & 7) * 4;           // 0,4,..,28
    float accv0[4] = {0, 0, 0, 0};
    float accv1[4] = {0, 0, 0, 0};

    for (int tt = t_begin; tt < t_end; tt++) {
        int s0 = tt << 6;
        int gs = s0 + sr;
        int4 kv = make_int4(0, 0, 0, 0), vv = make_int4(0, 0, 0, 0);
        if (gs < S) {
            kv = *(const int4*)&kp[((size_t)bh * S + gs) * 32 + sg * 8];
            vv = *(const int4*)&vp[((size_t)bh * S + gs) * 32 + sg * 8];
        }
        __syncthreads();   // previous iteration's reads of Ks/Vt/Ps complete
        *(int4*)&Ks[sr][sg * 8] = kv;
        {
            union { int4 v; ushort u[8]; } cv; cv.v = vv;
            int d0 = sg * 8;
#pragma unroll
            for (int jj = 0; jj < 8; jj++) Vt[d0 + jj][sr] = b2f(cv.u[jj]);
        }
        if (BIAS && t < 64) {
            gq2[t][0] = grid_xy[(size_t)(s0 + t) * 2 + 0];
            gq2[t][1] = grid_xy[(size_t)(s0 + t) * 2 + 1];
        }
        __syncthreads();

        // --- QK^T MFMA: D[row=q local lg*4+j][col=s f*16+lr]
        f32x4 sfrag[4];
#pragma unroll
        for (int f = 0; f < 4; f++) {
            s16x8 kf = *(const s16x8*)&Ks[f * 16 + lr][lg * 8];
            sfrag[f] = __builtin_amdgcn_mfma_f32_16x16x32_bf16(qfrag, kf, (f32x4)0.0f, 0, 0, 0);
        }
        // --- DIRECT-form bias + mask
#pragma unroll
        for (int f = 0; f < 4; f++) {
            int gsc = s0 + f * 16 + lr;
            if (BIAS) {
                float gx = gq2[f * 16 + lr][0];
                float gy = gq2[f * 16 + lr][1];
#pragma unroll
                for (int j = 0; j < 4; j++) {
                    float dx = px[j] - gx, dy = py[j] - gy;
                    sfrag[f][j] -= (sx[j] * dx * dx + sy[j] * dy * dy) * 0.125f;
                }
            }
            if (gsc >= S) {
#pragma unroll
                for (int j = 0; j < 4; j++) sfrag[f][j] = -INFINITY;
            }
        }
        // --- in-register online softmax per q row (16-lane group reduce)
        float sfv[4];
#pragma unroll
        for (int j = 0; j < 4; j++) {
            float mx = fmaxf(fmaxf(sfrag[0][j], sfrag[1][j]), fmaxf(sfrag[2][j], sfrag[3][j]));
            mx = fmaxf(mx, __shfl_xor(mx, 1));
            mx = fmaxf(mx, __shfl_xor(mx, 2));
            mx = fmaxf(mx, __shfl_xor(mx, 4));
            mx = fmaxf(mx, __shfl_xor(mx, 8));
            float mnew = fmaxf(m_run[j], mx);
            sfv[j] = __expf(m_run[j] - mnew);
            m_run[j] = mnew;
            float ps = 0.0f;
#pragma unroll
            for (int f = 0; f < 4; f++) {
                float p = __expf(sfrag[f][j] - mnew);
                sfrag[f][j] = p;
                ps += p;
            }
            ps += __shfl_xor(ps, 1);
            ps += __shfl_xor(ps, 2);
            ps += __shfl_xor(ps, 4);
            ps += __shfl_xor(ps, 8);
            l_run[j] = l_run[j] * sfv[j] + ps;
        }
        // --- write P fp32 + rescale factors, then barrier for PV threads
#pragma unroll
        for (int f = 0; f < 4; f++) {
#pragma unroll
            for (int j = 0; j < 4; j++) {
                Ps[w * 16 + lg * 4 + j][f * 16 + lr] = sfrag[f][j];
            }
        }
        if (lr == 0) {
#pragma unroll
            for (int j = 0; j < 4; j++) sf_s[w * 16 + lg * 4 + j] = sfv[j];
        }
        __syncthreads();

        // --- scalar fp32 PV (proven pattern): thread owns q2,q2+1 x dq..dq+3
        {
            float sf0 = sf_s[q2], sf1 = sf_s[q2 + 1];
#pragma unroll
            for (int d = 0; d < 4; d++) { accv0[d] *= sf0; accv1[d] *= sf1; }
#pragma unroll
            for (int s4 = 0; s4 < 16; s4++) {
                float4 p0 = *(const float4*)&Ps[q2][s4 * 4];
                float4 p1 = *(const float4*)&Ps[q2 + 1][s4 * 4];
#pragma unroll
                for (int d = 0; d < 4; d++) {
                    float4 v4 = *(const float4*)&Vt[dq + d][s4 * 4];
                    accv0[d] = fmaf(p0.x, v4.x, accv0[d]);
                    accv0[d] = fmaf(p0.y, v4.y, accv0[d]);
                    accv0[d] = fmaf(p0.z, v4.z, accv0[d]);
                    accv0[d] = fmaf(p0.w, v4.w, accv0[d]);
                    accv1[d] = fmaf(p1.x, v4.x, accv1[d]);
                    accv1[d] = fmaf(p1.y, v4.y, accv1[d]);
                    accv1[d] = fmaf(p1.z, v4.z, accv1[d]);
                    accv1[d] = fmaf(p1.w, v4.w, accv1[d]);
                }
            }
        }
    }

    // --- partials: m/l from compute lanes, acc from PV threads
    if (lr == 0) {
#pragma unroll
        for (int j = 0; j < 4; j++) {
            int row = q0 + w * 16 + lg * 4 + j;
            size_t pidx = (size_t)(chunk * 16 + bh) * ROWS + row;
            pm[pidx] = m_run[j];
            pl[pidx] = l_run[j];
        }
    }
    {
        size_t pidx0 = (size_t)(chunk * 16 + bh) * ROWS + (q0 + q2);
        size_t pidx1 = pidx0 + 1;
#pragma unroll
        for (int d = 0; d < 4; d++) {
            pacc[pidx0 * 32 + dq + d] = accv0[d];
            pacc[pidx1 * 32 + dq + d] = accv1[d];
        }
    }
}

// ---------------- combine partials ----------------
__global__ __launch_bounds__(256) void attn_combine(
    const float* __restrict__ pacc, const float* __restrict__ pm, const float* __restrict__ pl,
    float* __restrict__ outbuf, int NS, int ROWS, int L)
{
    int gid = blockIdx.x * 256 + threadIdx.x;
    if (gid >= 16 * L * 32) return;
    int d = gid & 31;
    int pr = gid >> 5;
    int bh = pr / L;
    int row = pr - bh * L;
    float M = -INFINITY;
    for (int c = 0; c < NS; c++) M = fmaxf(M, pm[(size_t)(c * 16 + bh) * ROWS + row]);
    float Lt = 0.0f, a = 0.0f;
    for (int c = 0; c < NS; c++) {
        size_t pidx = (size_t)(c * 16 + bh) * ROWS + row;
        float wgt = __expf(pm[pidx] - M);
        Lt = fmaf(pl[pidx], wgt, Lt);
        a = fmaf(pacc[pidx * 32 + d], wgt, a);
    }
    int b = bh >> 3, h = bh & 7;
    outbuf[((size_t)row * BN + b) * DN + h * 32 + d] = a / Lt;
}

// ---------------- workspace offsets (floats) ----------------
#define OFF_QK      0
#define OFF_LN4     153600
#define OFF_TMP     307200
#define OFF_H1      460800
#define OFF_H2      614400
#define OFF_POINT   768000
#define OFF_SCALE2  777600
#define OFF_SAQ     787200
#define OFF_SAK     940800
#define OFF_SAV     1094400
#define OFF_AOUT    1248000
#define OFF_X1      1401600
#define OFF_PACC    1555200   /* 8*16*320*32 = 1,310,720 */
#define OFF_PM      2865920   /* 40960 */
#define OFF_PL      2906880   /* 40960 */
#define OFF_MEMB    2947840   /* bf16 -> 1,048,576 float-equiv */
#define OFF_MPB     3996416
#define OFF_WKVB    5044992   /* 65,536 */
#define OFF_CAKB    5110528   /* bf16 1,048,576 float-equiv */
#define OFF_CAVB    6159104
#define OFF_XQ      7207680
#define OFF_XO      7361280
#define OFF_CAQ     7514880   /* fp32 CA1 Q head layout */
#define OFF_CAQ2B   7668480   /* bf16 CA2 Q: 153600 ushorts = 76800 floats */
#define OFF_AOUT2   7745280
#define OFF_AOUT3   7898880
#define OFF_X2      8052480
#define OFF_FFH     8206080   /* 1,228,800 */
// end: 9,434,880 floats = 37.7 MB

extern "C" void kernel_launch(void* const* d_in, const int* in_sizes, int n_in,
                              void* d_out, int out_size, void* d_ws, size_t ws_size,
                              hipStream_t stream)
{
    const float* grid_in   = (const float*)d_in[0];
    const float* h_w       = (const float*)d_in[1];
    const float* tgt       = (const float*)d_in[2];
    const float* memory    = (const float*)d_in[3];
    const float* pos       = (const float*)d_in[4];
    const float* query_pos = (const float*)d_in[5];
    const int*   ro1       = (const int*)d_in[6];
    const int*   ro2       = (const int*)d_in[7];
    const float* sa_Wi = (const float*)d_in[8];
    const float* sa_bi = (const float*)d_in[9];
    const float* sa_Wo = (const float*)d_in[10];
    const float* sa_bo = (const float*)d_in[11];
    const float* ca_Wi = (const float*)d_in[12];
    const float* ca_bi = (const float*)d_in[13];
    const float* ca_Wo = (const float*)d_in[14];
    const float* ca_bo = (const float*)d_in[15];
    const float* W1 = (const float*)d_in[16];
    const float* b1 = (const float*)d_in[17];
    const float* W2 = (const float*)d_in[18];
    const float* b2 = (const float*)d_in[19];
    const float* n1g = (const float*)d_in[20];
    const float* n1b = (const float*)d_in[21];
    const float* n2g = (const float*)d_in[22];
    const float* n2b = (const float*)d_in[23];
    const float* n3g = (const float*)d_in[24];
    const float* n3b = (const float*)d_in[25];
    const float* n4g = (const float*)d_in[26];
    const float* n4b = (const float*)d_in[27];
    const float* p1_W0 = (const float*)d_in[28];
    const float* p1_b0 = (const float*)d_in[29];
    const float* p1_W1 = (const float*)d_in[30];
    const float* p1_b1 = (const float*)d_in[31];
    const float* p1_W2 = (const float*)d_in[32];
    const float* p1_b2 = (const float*)d_in[33];
    const float* p2W = (const float*)d_in[34];
    const float* p2b = (const float*)d_in[35];
    const float* p3W = (const float*)d_in[36];
    const float* p3b = (const float*)d_in[37];

    float* ws  = (float*)d_ws;
    float* out = (float*)d_out;
    const float qscale = 0.1767766952966369f; // 32^-0.5

    ushort* memb  = (ushort*)(ws + OFF_MEMB);
    ushort* mpb   = (ushort*)(ws + OFF_MPB);
    ushort* wkvb  = (ushort*)(ws + OFF_WKVB);
    ushort* cakb  = (ushort*)(ws + OFF_CAKB);
    ushort* cavb  = (ushort*)(ws + OFF_CAVB);
    ushort* caq2b = (ushort*)(ws + OFF_CAQ2B);

    dim3 g600(600), b256(256);
    dim3 gS(19, 8);           // 32x32 fp32 gemm, M=600 N=256
    dim3 gFF1(19, 64);        // FFN1 N=2048
    dim3 gKV(128, 4);         // bf16 mfma gemm, M=8192 N=256

    // 1. ln4 = LN(tgt+query_pos); qk = tgt+query_pos
    addln_kernel<<<g600, b256, 0, stream>>>(tgt, query_pos, n4g, n4b, ws + OFF_LN4, ws + OFF_QK);
    // 2-3. point1 MLP hidden layers
    gemm_small<1><<<gS, b256, 0, stream>>>(ws + OFF_LN4, p1_W0, p1_b0, ws + OFF_H1, 600, 256, 256, 0, 1.f);
    gemm_small<1><<<gS, b256, 0, stream>>>(ws + OFF_H1, p1_W1, p1_b1, ws + OFF_H2, 600, 256, 256, 0, 1.f);
    // 4. tiny heads + ref/point/scale2
    small_heads<<<g600, dim3(64), 0, stream>>>(ws + OFF_LN4, ws + OFF_H2, p2W, p2b, p3W, p3b,
                                               p1_W2, p1_b2, h_w,
                                               out + 153600, out + 154800,
                                               ws + OFF_POINT, ws + OFF_SCALE2);
    // 5-7. SA projections (fp32 head layout)
    gemm_small<2><<<gS, b256, 0, stream>>>(ws + OFF_QK, sa_Wi,          sa_bi,       ws + OFF_SAQ, 600, 256, 256, 300, qscale);
    gemm_small<2><<<gS, b256, 0, stream>>>(ws + OFF_QK, sa_Wi + 65536,  sa_bi + 256, ws + OFF_SAK, 600, 256, 256, 300, 1.f);
    gemm_small<2><<<gS, b256, 0, stream>>>(tgt,         sa_Wi + 131072, sa_bi + 512, ws + OFF_SAV, 600, 256, 256, 300, 1.f);
    // 8-9. self-attention (fp32 proven) + combine
    attn_split<false, false><<<dim3(19, 16, 2), b256, 0, stream>>>(
        ws + OFF_SAQ, ws + OFF_SAK, ws + OFF_SAV, nullptr, nullptr, nullptr,
        ws + OFF_PACC, ws + OFF_PM, ws + OFF_PL, 300, 300, 3, 304);
    attn_combine<<<g600, b256, 0, stream>>>(ws + OFF_PACC, ws + OFF_PM, ws + OFF_PL,
                                            ws + OFF_AOUT, 2, 304, 300);
    // 10-11. SA out proj + LN1
    gemm_small<0><<<gS, b256, 0, stream>>>(ws + OFF_AOUT, sa_Wo, sa_bo, ws + OFF_TMP, 600, 256, 256, 0, 1.f);
    addln_kernel<<<g600, b256, 0, stream>>>(tgt, ws + OFF_TMP, n1g, n1b, ws + OFF_X1, nullptr);
    // 12-14. bf16 conversions for CA K/V gemms
    f2bf_kernel<<<dim3(1024), b256, 0, stream>>>(memory, memb, (SN * BN * DN) / 4);
    addvec_bf16_kernel<<<dim3(1024), b256, 0, stream>>>(memory, pos, mpb, (SN * BN * DN) / 4);
    f2bf_kernel<<<dim3(128), b256, 0, stream>>>(ca_Wi + 65536, wkvb, (2 * DN * DN) / 4);
    // 15-16. CA K/V projections (bf16 MFMA), bf16 head layout [bh][4096][32]
    gemm_bf16_mfma<<<gKV, b256, 0, stream>>>(mpb, wkvb, ca_bi + 256, cakb, 4096);
    gemm_bf16_mfma<<<gKV, b256, 0, stream>>>(memb, wkvb + 65536, ca_bi + 512, cavb, 4096);
    // 17. xq / xo
    build_xq_xo<<<g600, b256, 0, stream>>>(ws + OFF_X1, query_pos, ro1, ro2, ws + OFF_XQ, ws + OFF_XO);
    // 18-19. CA Q projections: CA1 fp32, CA2 bf16
    gemm_small<2><<<gS, b256, 0, stream>>>(ws + OFF_XQ, ca_Wi, ca_bi, ws + OFF_CAQ, 600, 256, 256, 300, qscale);
    gemm_small<4><<<gS, b256, 0, stream>>>(ws + OFF_XO, ca_Wi, ca_bi, (float*)caq2b, 600, 256, 256, 300, qscale);
    // 20-21. CA1: fp32 attention over bf16 K/V + combine -> AOUT2 (proven)
    attn_split<true, true><<<dim3(19, 16, 8), b256, 0, stream>>>(
        ws + OFF_CAQ, cakb, cavb, ws + OFF_POINT, ws + OFF_SCALE2, grid_in,
        ws + OFF_PACC, ws + OFF_PM, ws + OFF_PL, 4096, 300, 8, 304);
    attn_combine<<<g600, b256, 0, stream>>>(ws + OFF_PACC, ws + OFF_PM, ws + OFF_PL,
                                            ws + OFF_AOUT2, 8, 304, 300);
    // 22-23. CA2: HYBRID (MFMA QK + scalar PV, direct bias) + combine -> AOUT3
    attn_qkmfma<true><<<dim3(5, 16, 8), b256, 0, stream>>>(
        caq2b, cakb, cavb, ws + OFF_POINT, ws + OFF_SCALE2, grid_in,
        ws + OFF_PACC, ws + OFF_PM, ws + OFF_PL, 4096, 300, 8, 320);
    attn_combine<<<g600, b256, 0, stream>>>(ws + OFF_PACC, ws + OFF_PM, ws + OFF_PL,
                                            ws + OFF_AOUT3, 8, 320, 300);
    // 24-25. CA out projections
    gemm_small<0><<<gS, b256, 0, stream>>>(ws + OFF_AOUT2, ca_Wo, ca_bo, ws + OFF_TMP, 600, 256, 256, 0, 1.f);
    gemm_small<0><<<gS, b256, 0, stream>>>(ws + OFF_AOUT3, ca_Wo, ca_bo, out + 164400, 600, 256, 256, 0, 1.f);
    // 26. LN2
    addln_kernel<<<g600, b256, 0, stream>>>(ws + OFF_X1, ws + OFF_TMP, n2g, n2b, ws + OFF_X2, nullptr);
    // 27-28. FFN
    gemm_small<1><<<gFF1, b256, 0, stream>>>(ws + OFF_X2, W1, b1, ws + OFF_FFH, 600, 2048, 256, 0, 1.f);
    gemm_small<0><<<gS, b256, 0, stream>>>(ws + OFF_FFH, W2, b2, ws + OFF_TMP, 600, 256, 2048, 0, 1.f);
    // 29. LN3 -> x
    addln_kernel<<<g600, b256, 0, stream>>>(ws + OFF_X2, ws + OFF_TMP, n3g, n3b, out, nullptr);
}

// Round 9
// 671.994 us; speedup vs baseline: 1.0876x; 1.0876x over previous
//
#include <hip/hip_runtime.h>
#include <hip/hip_bf16.h>
#include <math.h>

// Problem constants
#define QN 300
#define BN 2
#define SN 4096
#define DN 256
#define HN 8
#define HD 32
#define BH 16
#define DFF 2048

typedef __attribute__((ext_vector_type(8))) short s16x8;
typedef __attribute__((ext_vector_type(4))) float f32x4;

// ---------------- helpers ----------------
__device__ inline float wred_sum(float v) {
#pragma unroll
    for (int m = 32; m > 0; m >>= 1) v += __shfl_xor(v, m);
    return v;
}
__device__ inline ushort f2b(float x) {
    union { __hip_bfloat16 h; ushort u; } c;
    c.h = __float2bfloat16(x);
    return c.u;
}
__device__ inline float b2f(ushort u) {
    union { unsigned int i; float f; } c;
    c.i = ((unsigned int)u) << 16;
    return c.f;
}

// ---------------- add + layernorm ----------------
__global__ __launch_bounds__(256) void addln_kernel(
    const float* __restrict__ a, const float* __restrict__ b,
    const float* __restrict__ g, const float* __restrict__ be,
    float* __restrict__ out_ln, float* __restrict__ out_sum)
{
    int row = blockIdx.x;
    int t = threadIdx.x;
    float v = a[row * DN + t] + b[row * DN + t];
    if (out_sum) out_sum[row * DN + t] = v;
    float s = wred_sum(v);
    float s2 = wred_sum(v * v);
    __shared__ float ws1[4], ws2[4];
    int wave = t >> 6, lane = t & 63;
    if (lane == 0) { ws1[wave] = s; ws2[wave] = s2; }
    __syncthreads();
    float S1 = ws1[0] + ws1[1] + ws1[2] + ws1[3];
    float S2 = ws2[0] + ws2[1] + ws2[2] + ws2[3];
    float mean = S1 * (1.0f / DN);
    float var = S2 * (1.0f / DN) - mean * mean;
    float inv = rsqrtf(var + 1e-5f);
    out_ln[row * DN + t] = (v - mean) * inv * g[t] + be[t];
}

// ---------------- fp32 -> bf16 conversions ----------------
__global__ void f2bf_kernel(const float* __restrict__ in, ushort* __restrict__ out, int n4)
{
    int i = blockIdx.x * blockDim.x + threadIdx.x;
    int stride = gridDim.x * blockDim.x;
    for (; i < n4; i += stride) {
        float4 x = ((const float4*)in)[i];
        ushort4 o;
        o.x = f2b(x.x); o.y = f2b(x.y); o.z = f2b(x.z); o.w = f2b(x.w);
        ((ushort4*)out)[i] = o;
    }
}
__global__ void addvec_bf16_kernel(const float* __restrict__ a, const float* __restrict__ b,
                                   ushort* __restrict__ out, int n4)
{
    int i = blockIdx.x * blockDim.x + threadIdx.x;
    int stride = gridDim.x * blockDim.x;
    for (; i < n4; i += stride) {
        float4 x = ((const float4*)a)[i];
        float4 y = ((const float4*)b)[i];
        ushort4 o;
        o.x = f2b(x.x + y.x); o.y = f2b(x.y + y.y);
        o.z = f2b(x.z + y.z); o.w = f2b(x.w + y.w);
        ((ushort4*)out)[i] = o;
    }
}

// ---------------- xq = x1+query_pos ; xo = x1+masked(query_pos) ----------------
__global__ __launch_bounds__(256) void build_xq_xo(
    const float* __restrict__ x1, const float* __restrict__ qp,
    const int* __restrict__ ro1, const int* __restrict__ ro2,
    float* __restrict__ xq, float* __restrict__ xo)
{
    int row = blockIdx.x, t = threadIdx.x;
    int q = row >> 1, b = row & 1;
    const int* ro = b ? ro2 : ro1;
    bool msk = (ro[q * 4 + 0] == 0) || (ro[q * 4 + 1] == 0) ||
               (ro[q * 4 + 2] == 0) || (ro[q * 4 + 3] == 0);
    float xv = x1[row * DN + t], qv = qp[row * DN + t];
    xq[row * DN + t] = xv + qv;
    xo[row * DN + t] = xv + (msk ? 0.0f : qv);
}

// ---------------- fp32 small GEMM 32x32 ----------------
// MODE 0: plain fp32; 1: relu fp32; 2: fp32 head layout [bh][seqLen][32] (*scale);
// MODE 4: bf16 head layout [bh][seqLen][32] (*scale)
template <int MODE>
__global__ __launch_bounds__(256) void gemm_small(
    const float* __restrict__ A, const float* __restrict__ W,
    const float* __restrict__ bias, float* __restrict__ C,
    int M, int N, int K, int seqLen, float scale)
{
    __shared__ float As[16][36];
    __shared__ float Bs[16][36];
    int bm = blockIdx.x * 32;
    int bn = blockIdx.y * 32;
    int t = threadIdx.x;
    int sr = (t & 127) >> 2;
    int sc = (t & 3) << 2;
    bool isB = t >= 128;
    int tm = (t >> 4) << 1;
    int tn = (t & 15) << 1;
    float acc[2][2] = {};
    int srcRow = (isB ? bn : bm) + sr;
    int lim = isB ? N : M;
    const float* src = isB ? W : A;
    for (int k0 = 0; k0 < K; k0 += 16) {
        float4 v = make_float4(0, 0, 0, 0);
        if (srcRow < lim) v = *(const float4*)&src[(size_t)srcRow * K + k0 + sc];
        __syncthreads();
        float (*Ts)[36] = isB ? Bs : As;
        Ts[sc + 0][sr] = v.x; Ts[sc + 1][sr] = v.y; Ts[sc + 2][sr] = v.z; Ts[sc + 3][sr] = v.w;
        __syncthreads();
#pragma unroll
        for (int kk = 0; kk < 16; kk++) {
            float2 a = *(const float2*)&As[kk][tm];
            float2 b = *(const float2*)&Bs[kk][tn];
            acc[0][0] = fmaf(a.x, b.x, acc[0][0]); acc[0][1] = fmaf(a.x, b.y, acc[0][1]);
            acc[1][0] = fmaf(a.y, b.x, acc[1][0]); acc[1][1] = fmaf(a.y, b.y, acc[1][1]);
        }
    }
#pragma unroll
    for (int i = 0; i < 2; i++) {
        int m = bm + tm + i;
        if (m >= M) continue;
#pragma unroll
        for (int j = 0; j < 2; j++) {
            int n = bn + tn + j;
            float v = acc[i][j] + bias[n];
            if (MODE == 1) v = fmaxf(v, 0.0f);
            if (MODE == 2) {
                v *= scale;
                int b = m & 1, seq = m >> 1, h = n >> 5, hd = n & 31;
                C[((size_t)(b * 8 + h) * seqLen + seq) * 32 + hd] = v;
            } else if (MODE == 4) {
                v *= scale;
                int b = m & 1, seq = m >> 1, h = n >> 5, hd = n & 31;
                ushort* Cb = (ushort*)C;
                Cb[((size_t)(b * 8 + h) * seqLen + seq) * 32 + hd] = f2b(v);
            } else {
                C[(size_t)m * N + n] = v;
            }
        }
    }
}

// ---------------- bf16 MFMA GEMM for K/V projections (verified r5/r6) ----------------
__global__ __launch_bounds__(256) void gemm_bf16_mfma(
    const ushort* __restrict__ A, const ushort* __restrict__ W,
    const float* __restrict__ bias, ushort* __restrict__ C, int seqLen)
{
    __shared__ ushort As[64][40];
    __shared__ ushort Ws[64][40];
    int bm = blockIdx.x * 64;
    int bn = blockIdx.y * 64;
    int t = threadIdx.x;
    int w = t >> 6, lane = t & 63;
    int lr = lane & 15, lg = lane >> 4;
    int sr = t >> 2, sg = t & 3;

    f32x4 acc[4];
#pragma unroll
    for (int f = 0; f < 4; f++) acc[f] = (f32x4)0.0f;

    for (int k0 = 0; k0 < 256; k0 += 32) {
        int4 av = *(const int4*)&A[((size_t)(bm + sr)) * 256 + k0 + sg * 8];
        int4 wv = *(const int4*)&W[((size_t)(bn + sr)) * 256 + k0 + sg * 8];
        __syncthreads();
        *(int4*)&As[sr][sg * 8] = av;
        *(int4*)&Ws[sr][sg * 8] = wv;
        __syncthreads();
        s16x8 af = *(const s16x8*)&As[w * 16 + lr][lg * 8];
#pragma unroll
        for (int f = 0; f < 4; f++) {
            s16x8 bf = *(const s16x8*)&Ws[f * 16 + lr][lg * 8];
            acc[f] = __builtin_amdgcn_mfma_f32_16x16x32_bf16(af, bf, acc[f], 0, 0, 0);
        }
    }
#pragma unroll
    for (int f = 0; f < 4; f++) {
#pragma unroll
        for (int j = 0; j < 4; j++) {
            int m = bm + w * 16 + lg * 4 + j;
            int n = bn + f * 16 + lr;
            float v = acc[f][j] + bias[n];
            int b = m & 1, seq = m >> 1, h = n >> 5, hd = n & 31;
            C[(((size_t)(b * 8 + h) * seqLen) + seq) * 32 + hd] = f2b(v);
        }
    }
}

// ---------------- small heads ----------------
__global__ __launch_bounds__(64) void small_heads(
    const float* __restrict__ ln4, const float* __restrict__ h2,
    const float* __restrict__ p2W, const float* __restrict__ p2b,
    const float* __restrict__ p3W, const float* __restrict__ p3b,
    const float* __restrict__ p1W2, const float* __restrict__ p1b2,
    const float* __restrict__ h_w,
    float* __restrict__ ref_inter_out, float* __restrict__ ref_out,
    float* __restrict__ point, float* __restrict__ scale2)
{
    int row = blockIdx.x;       // q*2+b
    int lane = threadIdx.x;     // 64
    __shared__ float rA[DN], rH[DN];
    __shared__ float po[16], sc[16], ri[2];
#pragma unroll
    for (int i = 0; i < 4; i++) {
        rA[lane + i * 64] = ln4[row * DN + lane + i * 64];
        rH[lane + i * 64] = h2[row * DN + lane + i * 64];
    }
    __syncthreads();
    for (int j = 0; j < 16; j++) {
        float p = 0;
#pragma unroll
        for (int i = 0; i < 4; i++) { int d = lane + i * 64; p = fmaf(rA[d], p2W[j * DN + d], p); }
        p = wred_sum(p);
        if (lane == 0) po[j] = p + p2b[j];
    }
    for (int j = 0; j < 16; j++) {
        float p = 0;
#pragma unroll
        for (int i = 0; i < 4; i++) { int d = lane + i * 64; p = fmaf(rA[d], p3W[j * DN + d], p); }
        p = wred_sum(p);
        if (lane == 0) sc[j] = p + p3b[j];
    }
    for (int j = 0; j < 2; j++) {
        float p = 0;
#pragma unroll
        for (int i = 0; i < 4; i++) { int d = lane + i * 64; p = fmaf(rH[d], p1W2[j * DN + d], p); }
        p = wred_sum(p);
        if (lane == 0) ri[j] = p + p1b2[j];
    }
    __syncthreads();
    int q = row >> 1, b = row & 1;
    float sig0 = 1.0f / (1.0f + expf(-ri[0]));
    float sig1 = 1.0f / (1.0f + expf(-ri[1]));
    float rx = h_w[b * 2 + 0] * sig0 * (1.0f / 32.0f);
    float ry = h_w[b * 2 + 1] * sig1 * (1.0f / 32.0f);
    if (lane < 2) ref_inter_out[row * 2 + lane] = ri[lane];
    if (lane < 16) {
        float rc = (lane & 1) ? ry : rx;
        ref_out[row * 16 + lane] = rc;
        int pidx = (q * 16 + b * 8 + (lane >> 1)) * 2 + (lane & 1);
        point[pidx] = rc + po[lane];
        float s = sc[lane];
        scale2[pidx] = s * s;
    }
}

// ---------------- HYBRID attention (verified r6): MFMA QK^T + in-reg softmax +
// direct Gaussian bias + scalar fp32 PV. All inputs bf16 head layout [bh][seq][32].
template <bool BIAS>
__global__ __launch_bounds__(256) void attn_qkmfma(
    const ushort* __restrict__ qp, const ushort* __restrict__ kp, const ushort* __restrict__ vp,
    const float* __restrict__ point, const float* __restrict__ scale2,
    const float* __restrict__ grid_xy,
    float* __restrict__ pacc, float* __restrict__ pm, float* __restrict__ pl,
    int S, int L, int tilesPerChunk, int ROWS)
{
    const int bh = blockIdx.y;
    const int q0 = blockIdx.x * 64;
    const int chunk = blockIdx.z;
    const int nT = (S + 63) >> 6;
    const int t_begin = chunk * tilesPerChunk;
    const int t_end = min(nT, t_begin + tilesPerChunk);

    __shared__ ushort Ks[64][40];   // K bf16 [s][d]
    __shared__ float Vt[32][68];    // V fp32 transposed [d][s]
    __shared__ float Ps[64][68];    // P fp32 [q_local][s]
    __shared__ float sf_s[64];
    __shared__ float gq2[64][2];    // gx, gy per s
    __shared__ float qc[64][4];     // px, py, sx, sy per local q

    int t = threadIdx.x;
    int w = t >> 6, lane = t & 63;
    int lr = lane & 15, lg = lane >> 4;
    int sr = t >> 2, sg = t & 3;

    // Q fragment (bf16, A-operand: lane row lr, k-octet lg)
    s16x8 qfrag;
    {
        int qrow = q0 + w * 16 + lr;
        if (qrow < L) qfrag = *(const s16x8*)&qp[((size_t)bh * L + qrow) * 32 + lg * 8];
        else qfrag = (s16x8)(short)0;
    }

    float px[4], py[4], sx[4], sy[4];
    if (BIAS) {
        if (t < 64) {
            int q = q0 + t;
            float a = 0, b = 0, c = 0, d = 0;
            if (q < L) {
                a = point[(q * 16 + bh) * 2 + 0];
                b = point[(q * 16 + bh) * 2 + 1];
                c = scale2[(q * 16 + bh) * 2 + 0];
                d = scale2[(q * 16 + bh) * 2 + 1];
            }
            qc[t][0] = a; qc[t][1] = b; qc[t][2] = c; qc[t][3] = d;
        }
        __syncthreads();
#pragma unroll
        for (int j = 0; j < 4; j++) {
            int ql = w * 16 + lg * 4 + j;
            px[j] = qc[ql][0]; py[j] = qc[ql][1];
            sx[j] = qc[ql][2]; sy[j] = qc[ql][3];
        }
    }

    float m_run[4], l_run[4];
#pragma unroll
    for (int j = 0; j < 4; j++) { m_run[j] = -INFINITY; l_run[j] = 0.0f; }

    // scalar PV ownership: 2 q rows x 4 d per thread
    int q2 = (t >> 3) * 2;          // 0,2,..,62
    int dq = (t & 7) * 4;           // 0,4,..,28
    float accv0[4] = {0, 0, 0, 0};
    float accv1[4] = {0, 0, 0, 0};

    for (int tt = t_begin; tt < t_end; tt++) {
        int s0 = tt << 6;
        int gs = s0 + sr;
        int4 kv = make_int4(0, 0, 0, 0), vv = make_int4(0, 0, 0, 0);
        if (gs < S) {
            kv = *(const int4*)&kp[((size_t)bh * S + gs) * 32 + sg * 8];
            vv = *(const int4*)&vp[((size_t)bh * S + gs) * 32 + sg * 8];
        }
        __syncthreads();   // previous iteration's reads of Ks/Vt/Ps complete
        *(int4*)&Ks[sr][sg * 8] = kv;
        {
            union { int4 v; ushort u[8]; } cv; cv.v = vv;
            int d0 = sg * 8;
#pragma unroll
            for (int jj = 0; jj < 8; jj++) Vt[d0 + jj][sr] = b2f(cv.u[jj]);
        }
        if (BIAS && t < 64) {
            gq2[t][0] = grid_xy[(size_t)(s0 + t) * 2 + 0];
            gq2[t][1] = grid_xy[(size_t)(s0 + t) * 2 + 1];
        }
        __syncthreads();

        // --- QK^T MFMA: D[row=q local lg*4+j][col=s f*16+lr]
        f32x4 sfrag[4];
#pragma unroll
        for (int f = 0; f < 4; f++) {
            s16x8 kf = *(const s16x8*)&Ks[f * 16 + lr][lg * 8];
            sfrag[f] = __builtin_amdgcn_mfma_f32_16x16x32_bf16(qfrag, kf, (f32x4)0.0f, 0, 0, 0);
        }
        // --- DIRECT-form bias + mask
#pragma unroll
        for (int f = 0; f < 4; f++) {
            int gsc = s0 + f * 16 + lr;
            if (BIAS) {
                float gx = gq2[f * 16 + lr][0];
                float gy = gq2[f * 16 + lr][1];
#pragma unroll
                for (int j = 0; j < 4; j++) {
                    float dx = px[j] - gx, dy = py[j] - gy;
                    sfrag[f][j] -= (sx[j] * dx * dx + sy[j] * dy * dy) * 0.125f;
                }
            }
            if (gsc >= S) {
#pragma unroll
                for (int j = 0; j < 4; j++) sfrag[f][j] = -INFINITY;
            }
        }
        // --- in-register online softmax per q row (16-lane group reduce)
        float sfv[4];
#pragma unroll
        for (int j = 0; j < 4; j++) {
            float mx = fmaxf(fmaxf(sfrag[0][j], sfrag[1][j]), fmaxf(sfrag[2][j], sfrag[3][j]));
            mx = fmaxf(mx, __shfl_xor(mx, 1));
            mx = fmaxf(mx, __shfl_xor(mx, 2));
            mx = fmaxf(mx, __shfl_xor(mx, 4));
            mx = fmaxf(mx, __shfl_xor(mx, 8));
            float mnew = fmaxf(m_run[j], mx);
            sfv[j] = __expf(m_run[j] - mnew);
            m_run[j] = mnew;
            float ps = 0.0f;
#pragma unroll
            for (int f = 0; f < 4; f++) {
                float p = __expf(sfrag[f][j] - mnew);
                sfrag[f][j] = p;
                ps += p;
            }
            ps += __shfl_xor(ps, 1);
            ps += __shfl_xor(ps, 2);
            ps += __shfl_xor(ps, 4);
            ps += __shfl_xor(ps, 8);
            l_run[j] = l_run[j] * sfv[j] + ps;
        }
        // --- write P fp32 + rescale factors, then barrier for PV threads
#pragma unroll
        for (int f = 0; f < 4; f++) {
#pragma unroll
            for (int j = 0; j < 4; j++) {
                Ps[w * 16 + lg * 4 + j][f * 16 + lr] = sfrag[f][j];
            }
        }
        if (lr == 0) {
#pragma unroll
            for (int j = 0; j < 4; j++) sf_s[w * 16 + lg * 4 + j] = sfv[j];
        }
        __syncthreads();

        // --- scalar fp32 PV (proven pattern): thread owns q2,q2+1 x dq..dq+3
        {
            float sf0 = sf_s[q2], sf1 = sf_s[q2 + 1];
#pragma unroll
            for (int d = 0; d < 4; d++) { accv0[d] *= sf0; accv1[d] *= sf1; }
#pragma unroll
            for (int s4 = 0; s4 < 16; s4++) {
                float4 p0 = *(const float4*)&Ps[q2][s4 * 4];
                float4 p1 = *(const float4*)&Ps[q2 + 1][s4 * 4];
#pragma unroll
                for (int d = 0; d < 4; d++) {
                    float4 v4 = *(const float4*)&Vt[dq + d][s4 * 4];
                    accv0[d] = fmaf(p0.x, v4.x, accv0[d]);
                    accv0[d] = fmaf(p0.y, v4.y, accv0[d]);
                    accv0[d] = fmaf(p0.z, v4.z, accv0[d]);
                    accv0[d] = fmaf(p0.w, v4.w, accv0[d]);
                    accv1[d] = fmaf(p1.x, v4.x, accv1[d]);
                    accv1[d] = fmaf(p1.y, v4.y, accv1[d]);
                    accv1[d] = fmaf(p1.z, v4.z, accv1[d]);
                    accv1[d] = fmaf(p1.w, v4.w, accv1[d]);
                }
            }
        }
    }

    // --- partials: m/l from compute lanes, acc from PV threads
    if (lr == 0) {
#pragma unroll
        for (int j = 0; j < 4; j++) {
            int row = q0 + w * 16 + lg * 4 + j;
            size_t pidx = (size_t)(chunk * 16 + bh) * ROWS + row;
            pm[pidx] = m_run[j];
            pl[pidx] = l_run[j];
        }
    }
    {
        size_t pidx0 = (size_t)(chunk * 16 + bh) * ROWS + (q0 + q2);
        size_t pidx1 = pidx0 + 1;
#pragma unroll
        for (int d = 0; d < 4; d++) {
            pacc[pidx0 * 32 + dq + d] = accv0[d];
            pacc[pidx1 * 32 + dq + d] = accv1[d];
        }
    }
}

// ---------------- combine partials ----------------
__global__ __launch_bounds__(256) void attn_combine(
    const float* __restrict__ pacc, const float* __restrict__ pm, const float* __restrict__ pl,
    float* __restrict__ outbuf, int NS, int ROWS, int L)
{
    int gid = blockIdx.x * 256 + threadIdx.x;
    if (gid >= 16 * L * 32) return;
    int d = gid & 31;
    int pr = gid >> 5;
    int bh = pr / L;
    int row = pr - bh * L;
    float M = -INFINITY;
    for (int c = 0; c < NS; c++) M = fmaxf(M, pm[(size_t)(c * 16 + bh) * ROWS + row]);
    float Lt = 0.0f, a = 0.0f;
    for (int c = 0; c < NS; c++) {
        size_t pidx = (size_t)(c * 16 + bh) * ROWS + row;
        float wgt = __expf(pm[pidx] - M);
        Lt = fmaf(pl[pidx], wgt, Lt);
        a = fmaf(pacc[pidx * 32 + d], wgt, a);
    }
    int b = bh >> 3, h = bh & 7;
    outbuf[((size_t)row * BN + b) * DN + h * 32 + d] = a / Lt;
}

// ---------------- workspace offsets (floats) ----------------
#define OFF_QK      0
#define OFF_LN4     153600
#define OFF_TMP     307200
#define OFF_H1      460800
#define OFF_H2      614400
#define OFF_POINT   768000
#define OFF_SCALE2  777600
#define OFF_SAQ     787200   /* bf16 76800-float slot (kept at 153600 spacing) */
#define OFF_SAK     940800
#define OFF_SAV     1094400
#define OFF_AOUT    1248000
#define OFF_X1      1401600
#define OFF_PACC    1555200   /* 8*16*320*32 = 1,310,720 */
#define OFF_PM      2865920   /* 40960 */
#define OFF_PL      2906880   /* 40960 */
#define OFF_MEMB    2947840   /* bf16 -> 1,048,576 float-equiv */
#define OFF_MPB     3996416
#define OFF_WKVB    5044992   /* 65,536 */
#define OFF_CAKB    5110528   /* bf16 1,048,576 float-equiv */
#define OFF_CAVB    6159104
#define OFF_XQ      7207680
#define OFF_XO      7361280
#define OFF_CAQ     7514880   /* bf16 CA1 Q head layout */
#define OFF_CAQ2B   7668480   /* bf16 CA2 Q */
#define OFF_AOUT2   7745280
#define OFF_AOUT3   7898880
#define OFF_X2      8052480
#define OFF_FFH     8206080   /* 1,228,800 */
// end: 9,434,880 floats = 37.7 MB

extern "C" void kernel_launch(void* const* d_in, const int* in_sizes, int n_in,
                              void* d_out, int out_size, void* d_ws, size_t ws_size,
                              hipStream_t stream)
{
    const float* grid_in   = (const float*)d_in[0];
    const float* h_w       = (const float*)d_in[1];
    const float* tgt       = (const float*)d_in[2];
    const float* memory    = (const float*)d_in[3];
    const float* pos       = (const float*)d_in[4];
    const float* query_pos = (const float*)d_in[5];
    const int*   ro1       = (const int*)d_in[6];
    const int*   ro2       = (const int*)d_in[7];
    const float* sa_Wi = (const float*)d_in[8];
    const float* sa_bi = (const float*)d_in[9];
    const float* sa_Wo = (const float*)d_in[10];
    const float* sa_bo = (const float*)d_in[11];
    const float* ca_Wi = (const float*)d_in[12];
    const float* ca_bi = (const float*)d_in[13];
    const float* ca_Wo = (const float*)d_in[14];
    const float* ca_bo = (const float*)d_in[15];
    const float* W1 = (const float*)d_in[16];
    const float* b1 = (const float*)d_in[17];
    const float* W2 = (const float*)d_in[18];
    const float* b2 = (const float*)d_in[19];
    const float* n1g = (const float*)d_in[20];
    const float* n1b = (const float*)d_in[21];
    const float* n2g = (const float*)d_in[22];
    const float* n2b = (const float*)d_in[23];
    const float* n3g = (const float*)d_in[24];
    const float* n3b = (const float*)d_in[25];
    const float* n4g = (const float*)d_in[26];
    const float* n4b = (const float*)d_in[27];
    const float* p1_W0 = (const float*)d_in[28];
    const float* p1_b0 = (const float*)d_in[29];
    const float* p1_W1 = (const float*)d_in[30];
    const float* p1_b1 = (const float*)d_in[31];
    const float* p1_W2 = (const float*)d_in[32];
    const float* p1_b2 = (const float*)d_in[33];
    const float* p2W = (const float*)d_in[34];
    const float* p2b = (const float*)d_in[35];
    const float* p3W = (const float*)d_in[36];
    const float* p3b = (const float*)d_in[37];

    float* ws  = (float*)d_ws;
    float* out = (float*)d_out;
    const float qscale = 0.1767766952966369f; // 32^-0.5

    ushort* saqb  = (ushort*)(ws + OFF_SAQ);
    ushort* sakb  = (ushort*)(ws + OFF_SAK);
    ushort* savb  = (ushort*)(ws + OFF_SAV);
    ushort* memb  = (ushort*)(ws + OFF_MEMB);
    ushort* mpb   = (ushort*)(ws + OFF_MPB);
    ushort* wkvb  = (ushort*)(ws + OFF_WKVB);
    ushort* cakb  = (ushort*)(ws + OFF_CAKB);
    ushort* cavb  = (ushort*)(ws + OFF_CAVB);
    ushort* caq1b = (ushort*)(ws + OFF_CAQ);
    ushort* caq2b = (ushort*)(ws + OFF_CAQ2B);

    dim3 g600(600), b256(256);
    dim3 gS(19, 8);           // 32x32 fp32 gemm, M=600 N=256
    dim3 gFF1(19, 64);        // FFN1 N=2048
    dim3 gKV(128, 4);         // bf16 mfma gemm, M=8192 N=256
    dim3 gAttnCA(5, 16, 8);   // hybrid attention, CA (S=4096: 8 chunks x 8 tiles)
    dim3 gAttnSA(5, 16, 2);   // hybrid attention, SA (S=300: 2 chunks x 3 tiles)

    // 1. ln4 = LN(tgt+query_pos); qk = tgt+query_pos
    addln_kernel<<<g600, b256, 0, stream>>>(tgt, query_pos, n4g, n4b, ws + OFF_LN4, ws + OFF_QK);
    // 2-3. point1 MLP hidden layers
    gemm_small<1><<<gS, b256, 0, stream>>>(ws + OFF_LN4, p1_W0, p1_b0, ws + OFF_H1, 600, 256, 256, 0, 1.f);
    gemm_small<1><<<gS, b256, 0, stream>>>(ws + OFF_H1, p1_W1, p1_b1, ws + OFF_H2, 600, 256, 256, 0, 1.f);
    // 4. tiny heads + ref/point/scale2
    small_heads<<<g600, dim3(64), 0, stream>>>(ws + OFF_LN4, ws + OFF_H2, p2W, p2b, p3W, p3b,
                                               p1_W2, p1_b2, h_w,
                                               out + 153600, out + 154800,
                                               ws + OFF_POINT, ws + OFF_SCALE2);
    // 5-7. SA projections -> bf16 head layout (MODE 4, verified)
    gemm_small<4><<<gS, b256, 0, stream>>>(ws + OFF_QK, sa_Wi,          sa_bi,       (float*)saqb, 600, 256, 256, 300, qscale);
    gemm_small<4><<<gS, b256, 0, stream>>>(ws + OFF_QK, sa_Wi + 65536,  sa_bi + 256, (float*)sakb, 600, 256, 256, 300, 1.f);
    gemm_small<4><<<gS, b256, 0, stream>>>(tgt,         sa_Wi + 131072, sa_bi + 512, (float*)savb, 600, 256, 256, 300, 1.f);
    // 8-9. self-attention (hybrid) + combine
    attn_qkmfma<false><<<gAttnSA, b256, 0, stream>>>(
        saqb, sakb, savb, nullptr, nullptr, nullptr,
        ws + OFF_PACC, ws + OFF_PM, ws + OFF_PL, 300, 300, 3, 320);
    attn_combine<<<g600, b256, 0, stream>>>(ws + OFF_PACC, ws + OFF_PM, ws + OFF_PL,
                                            ws + OFF_AOUT, 2, 320, 300);
    // 10-11. SA out proj + LN1
    gemm_small<0><<<gS, b256, 0, stream>>>(ws + OFF_AOUT, sa_Wo, sa_bo, ws + OFF_TMP, 600, 256, 256, 0, 1.f);
    addln_kernel<<<g600, b256, 0, stream>>>(tgt, ws + OFF_TMP, n1g, n1b, ws + OFF_X1, nullptr);
    // 12-14. bf16 conversions for CA K/V gemms
    f2bf_kernel<<<dim3(1024), b256, 0, stream>>>(memory, memb, (SN * BN * DN) / 4);
    addvec_bf16_kernel<<<dim3(1024), b256, 0, stream>>>(memory, pos, mpb, (SN * BN * DN) / 4);
    f2bf_kernel<<<dim3(128), b256, 0, stream>>>(ca_Wi + 65536, wkvb, (2 * DN * DN) / 4);
    // 15-16. CA K/V projections (bf16 MFMA), bf16 head layout [bh][4096][32]
    gemm_bf16_mfma<<<gKV, b256, 0, stream>>>(mpb, wkvb, ca_bi + 256, cakb, 4096);
    gemm_bf16_mfma<<<gKV, b256, 0, stream>>>(memb, wkvb + 65536, ca_bi + 512, cavb, 4096);
    // 17. xq / xo
    build_xq_xo<<<g600, b256, 0, stream>>>(ws + OFF_X1, query_pos, ro1, ro2, ws + OFF_XQ, ws + OFF_XO);
    // 18-19. CA Q projections -> bf16 head layout
    gemm_small<4><<<gS, b256, 0, stream>>>(ws + OFF_XQ, ca_Wi, ca_bi, (float*)caq1b, 600, 256, 256, 300, qscale);
    gemm_small<4><<<gS, b256, 0, stream>>>(ws + OFF_XO, ca_Wi, ca_bi, (float*)caq2b, 600, 256, 256, 300, qscale);
    // 20-21. CA1 (hybrid) + combine -> AOUT2
    attn_qkmfma<true><<<gAttnCA, b256, 0, stream>>>(
        caq1b, cakb, cavb, ws + OFF_POINT, ws + OFF_SCALE2, grid_in,
        ws + OFF_PACC, ws + OFF_PM, ws + OFF_PL, 4096, 300, 8, 320);
    attn_combine<<<g600, b256, 0, stream>>>(ws + OFF_PACC, ws + OFF_PM, ws + OFF_PL,
                                            ws + OFF_AOUT2, 8, 320, 300);
    // 22-23. CA2 (hybrid) + combine -> AOUT3
    attn_qkmfma<true><<<gAttnCA, b256, 0, stream>>>(
        caq2b, cakb, cavb, ws + OFF_POINT, ws + OFF_SCALE2, grid_in,
        ws + OFF_PACC, ws + OFF_PM, ws + OFF_PL, 4096, 300, 8, 320);
    attn_combine<<<g600, b256, 0, stream>>>(ws + OFF_PACC, ws + OFF_PM, ws + OFF_PL,
                                            ws + OFF_AOUT3, 8, 320, 300);
    // 24-25. CA out projections
    gemm_small<0><<<gS, b256, 0, stream>>>(ws + OFF_AOUT2, ca_Wo, ca_bo, ws + OFF_TMP, 600, 256, 256, 0, 1.f);
    gemm_small<0><<<gS, b256, 0, stream>>>(ws + OFF_AOUT3, ca_Wo, ca_bo, out + 164400, 600, 256, 256, 0, 1.f);
    // 26. LN2
    addln_kernel<<<g600, b256, 0, stream>>>(ws + OFF_X1, ws + OFF_TMP, n2g, n2b, ws + OFF_X2, nullptr);
    // 27-28. FFN
    gemm_small<1><<<gFF1, b256, 0, stream>>>(ws + OFF_X2, W1, b1, ws + OFF_FFH, 600, 2048, 256, 0, 1.f);
    gemm_small<0><<<gS, b256, 0, stream>>>(ws + OFF_FFH, W2, b2, ws + OFF_TMP, 600, 256, 2048, 0, 1.f);
    // 29. LN3 -> x
    addln_kernel<<<g600, b256, 0, stream>>>(ws + OFF_X2, ws + OFF_TMP, n3g, n3b, out, nullptr);
}